// Round 17
// baseline (75.226 us; speedup 1.0000x reference)
//
#include <hip/hip_runtime.h>
#include <math.h>

#define B_ 4
#define T_ 512
#define C_ 128
#define HS_ 64

typedef float f4 __attribute__((ext_vector_type(4)));
typedef float f2 __attribute__((ext_vector_type(2)));

// scale = C^-0.5
#define SCALE_ 0.08838834764831845f

static __device__ __forceinline__ f2 relu2(f2 v) {
    v.x = fmaxf(v.x, 0.f);
    v.y = fmaxf(v.y, 0.f);
    return v;
}

// ---------------------------------------------------------------------------
// Kernel 1: prep.  x1 = x + pos_emb;  Aq = x1@W1q + b1;  AkT = (x1@W1k)^T;
// V = x@Wv.  256 blocks x 640 threads, block = 8 rows.  (round 10 verbatim)
// ---------------------------------------------------------------------------
__global__ __launch_bounds__(640) void k_prep(
    const float* __restrict__ x, const float* __restrict__ pos,
    const float* __restrict__ W1, const float* __restrict__ b1,
    const float* __restrict__ Wv,
    float* __restrict__ Aq, float* __restrict__ AkT, float* __restrict__ V)
{
    __shared__ float x1s[8 * 132];
    __shared__ float xs[8 * 132];
    const int t = threadIdx.x;
    const int row0 = blockIdx.x * 8;  // over B*T = 2048

    if (t < 256) {
        int r = t >> 5, cq = t & 31;
        int gr = row0 + r;
        f4 xv = *(const f4*)(x + gr * 128 + cq * 4);
        f4 pv = *(const f4*)(pos + (gr & 511) * 128 + cq * 4);
        *(f4*)&xs[r * 132 + cq * 4] = xv;
        *(f4*)&x1s[r * 132 + cq * 4] = xv + pv;
    }
    __syncthreads();

    const int q = t >> 3;   // 0..79 col-quad
    const int r = t & 7;    // row in tile

    const float* wbase;
    int wstr, col0;
    const float* xb;
    f4 binit = {0.f, 0.f, 0.f, 0.f};
    if (q < 32) {
        col0 = q * 4;
        wbase = W1 + 128 * 128 + col0;  // W1q rows (c-major)
        wstr = 128;
        xb = x1s;
        binit = *(const f4*)(b1 + col0);
    } else if (q < 64) {
        col0 = (q - 32) * 4;
        wbase = W1 + col0;  // W1k rows
        wstr = 128;
        xb = x1s;
    } else {
        col0 = (q - 64) * 4;
        wbase = Wv + col0;
        wstr = 64;
        xb = xs;
    }

    f4 acc = binit;
    const float* xr = xb + r * 132;
#pragma unroll 8
    for (int c = 0; c < 128; ++c) {
        f4 w = *(const f4*)(wbase + c * wstr);
        acc += xr[c] * w;
    }

    const int gr = row0 + r;
    if (q < 32) {
        *(f4*)(Aq + (size_t)gr * 128 + col0) = acc;
    } else if (q < 64) {
        const int bb = gr >> 9, j = gr & 511;
        float* base = AkT + ((size_t)bb * 128 + col0) * 512 + j;
        base[0]    = acc.x;
        base[512]  = acc.y;
        base[1024] = acc.z;
        base[1536] = acc.w;
    } else {
        *(f4*)(V + (size_t)gr * 64 + col0) = acc;
    }
}

// ---------------------------------------------------------------------------
// Kernel 2: fused wei + causal softmax + PV, ROW QUAD, balanced chunks
// (round 15 verbatim) — WITH A RUNTIME `reps` LOOP FOR INSTRUMENTATION.
// Each rep recomputes the identical result and rewrites out (idempotent,
// deterministic). reps=4 pushes this dispatch above the harness's ~39us
// fill kernels so rocprof's top-5 finally shows its counters, and
// dispatch_dur/4 measures the true per-pass cost. Barriers at rep end
// prevent cross-rep LDS races; runtime trip count prevents dedup.
// ---------------------------------------------------------------------------
__global__ __launch_bounds__(256, 4) void k_fused(
    const float* __restrict__ Aq, const float* __restrict__ AkT,
    const float* __restrict__ Vv, const float* __restrict__ W2,
    float* __restrict__ out, int reps)
{
    __shared__ float pbuf[4][4][128];
    __shared__ float accs[4][4][64];
    __shared__ float mls[4][4][2];

    const int t = threadIdx.x;
    const int bx = blockIdx.x;         // 0..511
    const int b = bx & 3;
    const int g = 127 - (bx >> 2);     // descending: heavy quads first
    const int r0 = g * 4;
    const int w = t >> 6, lane = t & 63;

    const int nj = r0 + 4;                      // live j count for this quad
    const int cj = ((nj + 7) >> 3) << 1;        // per-wave chunk, even, <=128
    const int jstart = w * cj;
    const int jend = min(jstart + cj, nj);
    const int jA = jstart + lane * 2;

    for (int rep = 0; rep < reps; ++rep) {
        float m0 = -1e30f, m1 = -1e30f, m2 = -1e30f, m3 = -1e30f;
        float l0 = 0.f, l1 = 0.f, l2 = 0.f, l3 = 0.f;
        float a0 = 0.f, a1 = 0.f, a2 = 0.f, a3 = 0.f;

        if (jstart < jend) {
            const float* aq0 = Aq + (size_t)(b * 512 + r0) * 128;
            const float* aq1 = aq0 + 128;
            const float* aq2 = aq1 + 128;
            const float* aq3 = aq2 + 128;
            const float* akt = AkT + (size_t)b * 65536 + jA;

            f2 s0a = {0,0}, s0b = {0,0}, s1a = {0,0}, s1b = {0,0};
            f2 s2a = {0,0}, s2b = {0,0}, s3a = {0,0}, s3b = {0,0};
#pragma unroll 4
            for (int c = 0; c < 128; c += 2) {
                const f2 k0 = *(const f2*)(akt + (size_t)c * 512);
                const f2 k1 = *(const f2*)(akt + (size_t)(c + 1) * 512);
                const float w0 = W2[c], w1 = W2[c + 1];
                s0a += relu2(k0 + aq0[c]) * w0;  s0b += relu2(k1 + aq0[c + 1]) * w1;
                s1a += relu2(k0 + aq1[c]) * w0;  s1b += relu2(k1 + aq1[c + 1]) * w1;
                s2a += relu2(k0 + aq2[c]) * w0;  s2b += relu2(k1 + aq2[c + 1]) * w1;
                s3a += relu2(k0 + aq3[c]) * w0;  s3b += relu2(k1 + aq3[c + 1]) * w1;
            }

#define FINROW(R, SA, SB, MD, LD)                                        \
            {                                                            \
                const int rr_ = r0 + (R);                                \
                const int jlim_ = min(jend - 1, rr_);                    \
                f2 sv = (SA + SB) * SCALE_;                              \
                float sx = (jA     <= jlim_) ? sv.x : -1e30f;            \
                float sy = (jA + 1 <= jlim_) ? sv.y : -1e30f;            \
                float mx = fmaxf(sx, sy);                                \
                _Pragma("unroll")                                        \
                for (int off = 1; off < 64; off <<= 1)                   \
                    mx = fmaxf(mx, __shfl_xor(mx, off));                 \
                const bool live_ = (jstart <= rr_);                      \
                const float px = live_ ? __expf(sx - mx) : 0.f;          \
                const float py = live_ ? __expf(sy - mx) : 0.f;          \
                f2 pp = {px, py};                                        \
                *(f2*)&pbuf[w][R][lane * 2] = pp;                        \
                float ls = px + py;                                      \
                _Pragma("unroll")                                        \
                for (int off = 1; off < 64; off <<= 1)                   \
                    ls += __shfl_xor(ls, off);                           \
                MD = live_ ? mx : -1e30f;                                \
                LD = ls;                                                 \
            }
            FINROW(0, s0a, s0b, m0, l0)
            FINROW(1, s1a, s1b, m1, l1)
            FINROW(2, s2a, s2b, m2, l2)
            FINROW(3, s3a, s3b, m3, l3)
#undef FINROW

            // ---- PV over the chunk; lane = h; V loads shared by 4 rows ----
            const float* vt = Vv + ((size_t)b * 512 + jstart) * 64 + lane;
            const int q4max = (jend - jstart + 3) >> 2;
            for (int q4 = 0; q4 < q4max; ++q4) {
                const f4 p0 = *(const f4*)&pbuf[w][0][q4 * 4];
                const f4 p1 = *(const f4*)&pbuf[w][1][q4 * 4];
                const f4 p2 = *(const f4*)&pbuf[w][2][q4 * 4];
                const f4 p3 = *(const f4*)&pbuf[w][3][q4 * 4];
                const float v0 = vt[(q4 * 4 + 0) * 64];
                const float v1 = vt[(q4 * 4 + 1) * 64];
                const float v2 = vt[(q4 * 4 + 2) * 64];
                const float v3 = vt[(q4 * 4 + 3) * 64];
                a0 += p0.x * v0 + p0.y * v1 + p0.z * v2 + p0.w * v3;
                a1 += p1.x * v0 + p1.y * v1 + p1.z * v2 + p1.w * v3;
                a2 += p2.x * v0 + p2.y * v1 + p2.z * v2 + p2.w * v3;
                a3 += p3.x * v0 + p3.y * v1 + p3.z * v2 + p3.w * v3;
            }
        }

        // ---- partials to LDS; in-block flash merge ----
        accs[w][0][lane] = a0;
        accs[w][1][lane] = a1;
        accs[w][2][lane] = a2;
        accs[w][3][lane] = a3;
        if (lane == 0) {
            mls[w][0][0] = m0; mls[w][0][1] = l0;
            mls[w][1][0] = m1; mls[w][1][1] = l1;
            mls[w][2][0] = m2; mls[w][2][1] = l2;
            mls[w][3][0] = m3; mls[w][3][1] = l3;
        }
        __syncthreads();

        // wave w merges row r0 + w over all 4 wave partials
        const int rr = r0 + w;
        float ms = -1e30f;
#pragma unroll
        for (int ww = 0; ww < 4; ++ww) ms = fmaxf(ms, mls[ww][w][0]);
        float num = 0.f, den = 0.f;
#pragma unroll
        for (int ww = 0; ww < 4; ++ww) {
            const float e = __expf(mls[ww][w][0] - ms);
            den += mls[ww][w][1] * e;
            num += accs[ww][w][lane] * e;
        }
        out[(size_t)(b * 512 + rr) * 64 + lane] = num / den;

        __syncthreads();  // rep isolation: accs/mls/pbuf reuse next rep
    }
}

// ---------------------------------------------------------------------------
extern "C" void kernel_launch(void* const* d_in, const int* in_sizes, int n_in,
                              void* d_out, int out_size, void* d_ws, size_t ws_size,
                              hipStream_t stream)
{
    const float* x   = (const float*)d_in[0];
    const float* pos = (const float*)d_in[1];
    const float* W1  = (const float*)d_in[2];
    const float* b1  = (const float*)d_in[3];
    const float* W2  = (const float*)d_in[4];
    const float* b2  = (const float*)d_in[5];  (void)b2;  // cancels in softmax
    const float* Wv  = (const float*)d_in[6];
    float* out = (float*)d_out;
    float* ws = (float*)d_ws;

    float* Aq  = ws;                 // B*T*C = 262144
    float* AkT = ws + 262144;        // B*C*T = 262144 (transposed)
    float* V   = ws + 524288;        // B*T*HS = 131072

    k_prep<<<dim3(256), dim3(640), 0, stream>>>(x, pos, W1, b1, Wv, Aq, AkT, V);
    k_fused<<<dim3(512), dim3(256), 0, stream>>>(Aq, AkT, V, W2, out, 4);
}

// Round 18
// 66.493 us; speedup vs baseline: 1.1313x; 1.1313x over previous
//
#include <hip/hip_runtime.h>
#include <math.h>

#define B_ 4
#define T_ 512
#define C_ 128
#define HS_ 64

typedef float f4 __attribute__((ext_vector_type(4)));

// scale = C^-0.5
#define SCALE_ 0.08838834764831845f

// ---------------------------------------------------------------------------
// Kernel 1: prep.  x1 = x + pos_emb;  Aq = x1@W1q + b1;  AkT = (x1@W1k)^T;
// V = x@Wv.  256 blocks x 640 threads, block = 8 rows.  (round 10 verbatim)
// ---------------------------------------------------------------------------
__global__ __launch_bounds__(640) void k_prep(
    const float* __restrict__ x, const float* __restrict__ pos,
    const float* __restrict__ W1, const float* __restrict__ b1,
    const float* __restrict__ Wv,
    float* __restrict__ Aq, float* __restrict__ AkT, float* __restrict__ V)
{
    __shared__ float x1s[8 * 132];
    __shared__ float xs[8 * 132];
    const int t = threadIdx.x;
    const int row0 = blockIdx.x * 8;  // over B*T = 2048

    if (t < 256) {
        int r = t >> 5, cq = t & 31;
        int gr = row0 + r;
        f4 xv = *(const f4*)(x + gr * 128 + cq * 4);
        f4 pv = *(const f4*)(pos + (gr & 511) * 128 + cq * 4);
        *(f4*)&xs[r * 132 + cq * 4] = xv;
        *(f4*)&x1s[r * 132 + cq * 4] = xv + pv;
    }
    __syncthreads();

    const int q = t >> 3;   // 0..79 col-quad
    const int r = t & 7;    // row in tile

    const float* wbase;
    int wstr, col0;
    const float* xb;
    f4 binit = {0.f, 0.f, 0.f, 0.f};
    if (q < 32) {
        col0 = q * 4;
        wbase = W1 + 128 * 128 + col0;  // W1q rows (c-major)
        wstr = 128;
        xb = x1s;
        binit = *(const f4*)(b1 + col0);
    } else if (q < 64) {
        col0 = (q - 32) * 4;
        wbase = W1 + col0;  // W1k rows
        wstr = 128;
        xb = x1s;
    } else {
        col0 = (q - 64) * 4;
        wbase = Wv + col0;
        wstr = 64;
        xb = xs;
    }

    f4 acc = binit;
    const float* xr = xb + r * 132;
#pragma unroll 8
    for (int c = 0; c < 128; ++c) {
        f4 w = *(const f4*)(wbase + c * wstr);
        acc += xr[c] * w;
    }

    const int gr = row0 + r;
    if (q < 32) {
        *(f4*)(Aq + (size_t)gr * 128 + col0) = acc;
    } else if (q < 64) {
        const int bb = gr >> 9, j = gr & 511;
        float* base = AkT + ((size_t)bb * 128 + col0) * 512 + j;
        base[0]    = acc.x;
        base[512]  = acc.y;
        base[1024] = acc.z;
        base[1536] = acc.w;
    } else {
        *(f4*)(V + (size_t)gr * 64 + col0) = acc;
    }
}

// ---------------------------------------------------------------------------
// Kernel 2: fused S + window softmax partials — FULL-LANE-UTILIZATION tiling.
// R17 counters: VALUBusy 55% but only ~50% of computed j-slots were live
// (2-j-per-lane waves with chunks cj<<128). Now: R11's verified enumeration
// of live (16-row group G, 64-j window w) pairs — 144 blocks/batch, ALL
// equal cost; block = 4 waves, wave = row-quad x window, lane = ONE j.
// ~90% of computed slots are causally live. Inner loop = R15-style direct
// loads: AkT column read coalesced (64 lanes x 4B over j), aq/W2 as f4
// wave-uniform loads, 3 VALU per (row,j,c). No LDS staging, no barriers.
// Per (row,window) flash partial (m,l,acc[64]) -> workspace; k_merge combines.
// ---------------------------------------------------------------------------
__global__ __launch_bounds__(256) void k_fusedp(
    const float* __restrict__ Aq, const float* __restrict__ AkT,
    const float* __restrict__ Vv, const float* __restrict__ W2,
    float* __restrict__ pml, float* __restrict__ pacc)
{
    __shared__ float pbuf[4][4][64];

    const int t = threadIdx.x;
    const int b = blockIdx.y;
    const int f = blockIdx.x;         // 0..143

    // decode band: n windows for G in [4(n-1), 4n); cum before band = 2n(n-1)
    int n = (int)((1.0f + sqrtf(1.0f + 2.0f * (float)f)) * 0.5f);
    while (2 * n * (n - 1) > f) --n;
    while (2 * n * (n + 1) <= f) ++n;
    const int rem = f - 2 * n * (n - 1);
    const int G = 4 * (n - 1) + rem / n;  // 0..31
    const int w = rem % n;                // window index (64-j)
    const int j0 = w * 64;

    const int w8 = t >> 6, lane = t & 63;
    const int r0 = G * 16 + w8 * 4;       // this wave's row quad
    const int gj = j0 + lane;             // this lane's j

    const float* aq0 = Aq + (size_t)(b * 512 + r0) * 128;
    const float* aq1 = aq0 + 128;
    const float* aq2 = aq1 + 128;
    const float* aq3 = aq2 + 128;
    const float* akc = AkT + (size_t)b * 65536 + gj;   // + c*512 walks c

    // ---- S over 128 c; 4 rows; 1 j/lane; coalesced ak column loads ----
    float s0 = 0.f, s1 = 0.f, s2 = 0.f, s3 = 0.f;
#pragma unroll 8
    for (int cq = 0; cq < 32; ++cq) {
        const f4 q0 = *(const f4*)(aq0 + cq * 4);   // wave-uniform f4
        const f4 q1 = *(const f4*)(aq1 + cq * 4);
        const f4 q2 = *(const f4*)(aq2 + cq * 4);
        const f4 q3 = *(const f4*)(aq3 + cq * 4);
        const f4 wq = *(const f4*)(W2 + cq * 4);
#pragma unroll
        for (int ch = 0; ch < 4; ++ch) {
            const float ak = akc[(size_t)(cq * 4 + ch) * 512];
            s0 += fmaxf(ak + q0[ch], 0.f) * wq[ch];
            s1 += fmaxf(ak + q1[ch], 0.f) * wq[ch];
            s2 += fmaxf(ak + q2[ch], 0.f) * wq[ch];
            s3 += fmaxf(ak + q3[ch], 0.f) * wq[ch];
        }
    }

    float m0, m1, m2, m3, l0, l1, l2, l3;
#define FINROW(R, SS, MD, LD)                                            \
    {                                                                    \
        const int rr_ = r0 + (R);                                        \
        float sx = (gj <= rr_) ? (SS) * SCALE_ : -1e30f;                 \
        float mx = sx;                                                   \
        _Pragma("unroll")                                                \
        for (int off = 1; off < 64; off <<= 1)                           \
            mx = fmaxf(mx, __shfl_xor(mx, off));                         \
        const bool live_ = (j0 <= rr_);                                  \
        const float p = live_ ? __expf(sx - mx) : 0.f;                   \
        pbuf[w8][R][lane] = p;                                           \
        float ls = p;                                                    \
        _Pragma("unroll")                                                \
        for (int off = 1; off < 64; off <<= 1)                           \
            ls += __shfl_xor(ls, off);                                   \
        MD = live_ ? mx : -1e30f;                                        \
        LD = ls;                                                         \
    }
    FINROW(0, s0, m0, l0)
    FINROW(1, s1, m1, l1)
    FINROW(2, s2, m2, l2)
    FINROW(3, s3, m3, l3)
#undef FINROW

    // ---- PV over the window; lane = h; V loads shared by 4 rows ----
    const float* vt = Vv + ((size_t)b * 512 + j0) * 64 + lane;
    float a0 = 0.f, a1 = 0.f, a2 = 0.f, a3 = 0.f;
#pragma unroll 4
    for (int q4 = 0; q4 < 16; ++q4) {
        const f4 p0 = *(const f4*)&pbuf[w8][0][q4 * 4];
        const f4 p1 = *(const f4*)&pbuf[w8][1][q4 * 4];
        const f4 p2 = *(const f4*)&pbuf[w8][2][q4 * 4];
        const f4 p3 = *(const f4*)&pbuf[w8][3][q4 * 4];
        const float v0 = vt[(q4 * 4 + 0) * 64];
        const float v1 = vt[(q4 * 4 + 1) * 64];
        const float v2 = vt[(q4 * 4 + 2) * 64];
        const float v3 = vt[(q4 * 4 + 3) * 64];
        a0 += p0.x * v0 + p0.y * v1 + p0.z * v2 + p0.w * v3;
        a1 += p1.x * v0 + p1.y * v1 + p1.z * v2 + p1.w * v3;
        a2 += p2.x * v0 + p2.y * v1 + p2.z * v2 + p2.w * v3;
        a3 += p3.x * v0 + p3.y * v1 + p3.z * v2 + p3.w * v3;
    }

    // ---- write partials: key = (global row)*8 + w ----
    const size_t k0 = ((size_t)(b * 512 + r0) * 8 + w);
    pacc[(k0 + 0 ) * 64 + lane] = a0;
    pacc[(k0 + 8 ) * 64 + lane] = a1;
    pacc[(k0 + 16) * 64 + lane] = a2;
    pacc[(k0 + 24) * 64 + lane] = a3;
    if (lane == 0) {
        pml[(k0 + 0 ) * 2] = m0;  pml[(k0 + 0 ) * 2 + 1] = l0;
        pml[(k0 + 8 ) * 2] = m1;  pml[(k0 + 8 ) * 2 + 1] = l1;
        pml[(k0 + 16) * 2] = m2;  pml[(k0 + 16) * 2 + 1] = l2;
        pml[(k0 + 24) * 2] = m3;  pml[(k0 + 24) * 2 + 1] = l3;
    }
}

// ---------------------------------------------------------------------------
// Kernel 3: merge. One wave per row; flash-combine its nw = i/64 + 1
// window partials. Reads only w <= i>>6 (always written by k_fusedp).
// (round 11 verbatim — verified)
// ---------------------------------------------------------------------------
__global__ __launch_bounds__(256) void k_merge(
    const float* __restrict__ pml, const float* __restrict__ pacc,
    float* __restrict__ out)
{
    const int t = threadIdx.x;
    const int w8 = t >> 6, lane = t & 63;
    const int grow = blockIdx.x * 4 + w8;   // 0..2047
    const int i = grow & 511;
    const int nw = (i >> 6) + 1;
    const size_t base = (size_t)grow * 8;

    float ms = -1e30f;
    for (int w = 0; w < nw; ++w) ms = fmaxf(ms, pml[(base + w) * 2]);
    float num = 0.f, den = 0.f;
    for (int w = 0; w < nw; ++w) {
        const float e = __expf(pml[(base + w) * 2] - ms);
        den += pml[(base + w) * 2 + 1] * e;
        num += pacc[(base + w) * 64 + lane] * e;
    }
    out[(size_t)grow * 64 + lane] = num / den;
}

// ---------------------------------------------------------------------------
extern "C" void kernel_launch(void* const* d_in, const int* in_sizes, int n_in,
                              void* d_out, int out_size, void* d_ws, size_t ws_size,
                              hipStream_t stream)
{
    const float* x   = (const float*)d_in[0];
    const float* pos = (const float*)d_in[1];
    const float* W1  = (const float*)d_in[2];
    const float* b1  = (const float*)d_in[3];
    const float* W2  = (const float*)d_in[4];
    const float* b2  = (const float*)d_in[5];  (void)b2;  // cancels in softmax
    const float* Wv  = (const float*)d_in[6];
    float* out = (float*)d_out;
    float* ws = (float*)d_ws;

    float* Aq   = ws;                 // B*T*C   = 262144
    float* AkT  = ws + 262144;        // B*C*T   = 262144 (transposed)
    float* V    = ws + 524288;        // B*T*HS  = 131072
    float* pml  = ws + 655360;        // 2048*8*2  = 32768
    float* pacc = ws + 688128;        // 2048*8*64 = 1048576

    k_prep<<<dim3(256), dim3(640), 0, stream>>>(x, pos, W1, b1, Wv, Aq, AkT, V);
    k_fusedp<<<dim3(144, B_), dim3(256), 0, stream>>>(Aq, AkT, V, W2, pml, pacc);
    k_merge<<<dim3(512), dim3(256), 0, stream>>>(pml, pacc, out);
}

// Round 19
// 40.135 us; speedup vs baseline: 1.8743x; 1.6567x over previous
//
#include <hip/hip_runtime.h>
#include <math.h>

#define B_ 4
#define T_ 512
#define C_ 128
#define HS_ 64

typedef float f4 __attribute__((ext_vector_type(4)));

// scale = C^-0.5
#define SCALE_ 0.08838834764831845f

// ---------------------------------------------------------------------------
// Kernel 1: prep.  x1 = x + pos_emb;  Aq = x1@W1q + b1;  AkT = (x1@W1k)^T;
// V = x@Wv.  256 blocks x 640 threads, block = 8 rows.  (round 10 verbatim)
// ---------------------------------------------------------------------------
__global__ __launch_bounds__(640) void k_prep(
    const float* __restrict__ x, const float* __restrict__ pos,
    const float* __restrict__ W1, const float* __restrict__ b1,
    const float* __restrict__ Wv,
    float* __restrict__ Aq, float* __restrict__ AkT, float* __restrict__ V)
{
    __shared__ float x1s[8 * 132];
    __shared__ float xs[8 * 132];
    const int t = threadIdx.x;
    const int row0 = blockIdx.x * 8;  // over B*T = 2048

    if (t < 256) {
        int r = t >> 5, cq = t & 31;
        int gr = row0 + r;
        f4 xv = *(const f4*)(x + gr * 128 + cq * 4);
        f4 pv = *(const f4*)(pos + (gr & 511) * 128 + cq * 4);
        *(f4*)&xs[r * 132 + cq * 4] = xv;
        *(f4*)&x1s[r * 132 + cq * 4] = xv + pv;
    }
    __syncthreads();

    const int q = t >> 3;   // 0..79 col-quad
    const int r = t & 7;    // row in tile

    const float* wbase;
    int wstr, col0;
    const float* xb;
    f4 binit = {0.f, 0.f, 0.f, 0.f};
    if (q < 32) {
        col0 = q * 4;
        wbase = W1 + 128 * 128 + col0;  // W1q rows (c-major)
        wstr = 128;
        xb = x1s;
        binit = *(const f4*)(b1 + col0);
    } else if (q < 64) {
        col0 = (q - 32) * 4;
        wbase = W1 + col0;  // W1k rows
        wstr = 128;
        xb = x1s;
    } else {
        col0 = (q - 64) * 4;
        wbase = Wv + col0;
        wstr = 64;
        xb = xs;
    }

    f4 acc = binit;
    const float* xr = xb + r * 132;
#pragma unroll 8
    for (int c = 0; c < 128; ++c) {
        f4 w = *(const f4*)(wbase + c * wstr);
        acc += xr[c] * w;
    }

    const int gr = row0 + r;
    if (q < 32) {
        *(f4*)(Aq + (size_t)gr * 128 + col0) = acc;
    } else if (q < 64) {
        const int bb = gr >> 9, j = gr & 511;
        float* base = AkT + ((size_t)bb * 128 + col0) * 512 + j;
        base[0]    = acc.x;
        base[512]  = acc.y;
        base[1024] = acc.z;
        base[1536] = acc.w;
    } else {
        *(f4*)(V + (size_t)gr * 64 + col0) = acc;
    }
}

// ---------------------------------------------------------------------------
// Kernel 2: fused S + window softmax partials — equal-work enumeration (R18)
// with WIDE ak loads (the R18 fix). Lane = (cq4 = lane>>4, jq = lane&15):
// one f4 load = 4 j's of one c-row; a wave-instr covers 4 c-rows x 64 j =
// 1KB. Only 32 ak VMEM instrs/wave (R18 had 128 + 160 uniform), fully
// unrolled + independent -> cold-L3 latency pipelined. aq (16 rows) + W2
// staged in LDS once (5 ds_read per 48 VALU). S-reduce: shfl_xor(16,32).
// Window softmax: per-lane f4 max/sum + shfl_xor(1,2,4,8) over jq.
// PV / partial writes / k_merge / enumeration: R18 verbatim (verified).
// ---------------------------------------------------------------------------
__global__ __launch_bounds__(256, 4) void k_fusedp(
    const float* __restrict__ Aq, const float* __restrict__ AkT,
    const float* __restrict__ Vv, const float* __restrict__ W2,
    float* __restrict__ pml, float* __restrict__ pacc)
{
    __shared__ float aqs[16][128];    // 8 KB
    __shared__ float w2s[128];
    __shared__ float pbuf[4][4][64];  // [wave][row][j] 4 KB

    const int t = threadIdx.x;
    const int b = blockIdx.y;
    const int f = blockIdx.x;         // 0..143

    // decode band: n windows for G in [4(n-1), 4n); cum before band = 2n(n-1)
    int n = (int)((1.0f + sqrtf(1.0f + 2.0f * (float)f)) * 0.5f);
    while (2 * n * (n - 1) > f) --n;
    while (2 * n * (n + 1) <= f) ++n;
    const int rem = f - 2 * n * (n - 1);
    const int G = 4 * (n - 1) + rem / n;  // 0..31
    const int w = rem % n;                // window index (64-j)
    const int j0 = w * 64;
    const int row0 = G * 16;

    // ---- stage Aq rows + W2 into LDS ----
    const float* aqg = Aq + (size_t)(b * 512 + row0) * 128;
    for (int idx = t; idx < 512; idx += 256) {    // 16 r x 32 f4
        int r = idx >> 5, cq = idx & 31;
        *(f4*)&aqs[r][cq * 4] = *(const f4*)(aqg + r * 128 + cq * 4);
    }
    if (t < 32) *(f4*)&w2s[t * 4] = *(const f4*)(W2 + t * 4);
    __syncthreads();

    const int w8 = t >> 6, lane = t & 63;
    const int rb = w8 * 4;               // wave's rows: row0+rb .. +3
    const int r0 = row0 + rb;
    const int cq4 = lane >> 4;           // 0..3  c-offset within 4-row bundle
    const int jq = lane & 15;            // 0..15 j-quad index

    // lane's ak pointer: column-quad jq of c-row (base + cq4)
    const float* akl = AkT + (size_t)b * 65536 + (size_t)cq4 * 512 + j0 + jq * 4;

    // ---- S: 32 f4 loads (4 c-rows x 64 j per wave-instr), LDS aq/w2 ----
    f4 s0 = {0,0,0,0}, s1 = s0, s2 = s0, s3 = s0;
#pragma unroll
    for (int base = 0; base < 128; base += 4) {
        const f4 ak = *(const f4*)(akl + (size_t)base * 512);
        const int c = base + cq4;
        const float wv = w2s[c];
        const float q0 = aqs[rb + 0][c];
        const float q1 = aqs[rb + 1][c];
        const float q2 = aqs[rb + 2][c];
        const float q3 = aqs[rb + 3][c];
        f4 t0 = ak + q0, t1 = ak + q1, t2 = ak + q2, t3 = ak + q3;
        t0.x = fmaxf(t0.x, 0.f); t0.y = fmaxf(t0.y, 0.f);
        t0.z = fmaxf(t0.z, 0.f); t0.w = fmaxf(t0.w, 0.f);
        t1.x = fmaxf(t1.x, 0.f); t1.y = fmaxf(t1.y, 0.f);
        t1.z = fmaxf(t1.z, 0.f); t1.w = fmaxf(t1.w, 0.f);
        t2.x = fmaxf(t2.x, 0.f); t2.y = fmaxf(t2.y, 0.f);
        t2.z = fmaxf(t2.z, 0.f); t2.w = fmaxf(t2.w, 0.f);
        t3.x = fmaxf(t3.x, 0.f); t3.y = fmaxf(t3.y, 0.f);
        t3.z = fmaxf(t3.z, 0.f); t3.w = fmaxf(t3.w, 0.f);
        s0 += t0 * wv;
        s1 += t1 * wv;
        s2 += t2 * wv;
        s3 += t3 * wv;
    }
    // reduce over the 4 cq4 groups (bits 4,5): full c-sum, replicated
#pragma unroll
    for (int off = 16; off <= 32; off <<= 1) {
        s0.x += __shfl_xor(s0.x, off); s0.y += __shfl_xor(s0.y, off);
        s0.z += __shfl_xor(s0.z, off); s0.w += __shfl_xor(s0.w, off);
        s1.x += __shfl_xor(s1.x, off); s1.y += __shfl_xor(s1.y, off);
        s1.z += __shfl_xor(s1.z, off); s1.w += __shfl_xor(s1.w, off);
        s2.x += __shfl_xor(s2.x, off); s2.y += __shfl_xor(s2.y, off);
        s2.z += __shfl_xor(s2.z, off); s2.w += __shfl_xor(s2.w, off);
        s3.x += __shfl_xor(s3.x, off); s3.y += __shfl_xor(s3.y, off);
        s3.z += __shfl_xor(s3.z, off); s3.w += __shfl_xor(s3.w, off);
    }

    const int jb = j0 + jq * 4;          // lane's first j
    float m0, m1, m2, m3, l0, l1, l2, l3;
#define FINROW(R, SS, MD, LD)                                            \
    {                                                                    \
        const int rr_ = r0 + (R);                                        \
        f4 sv;                                                           \
        sv.x = (jb     <= rr_) ? SS.x * SCALE_ : -1e30f;                 \
        sv.y = (jb + 1 <= rr_) ? SS.y * SCALE_ : -1e30f;                 \
        sv.z = (jb + 2 <= rr_) ? SS.z * SCALE_ : -1e30f;                 \
        sv.w = (jb + 3 <= rr_) ? SS.w * SCALE_ : -1e30f;                 \
        float mx = fmaxf(fmaxf(sv.x, sv.y), fmaxf(sv.z, sv.w));          \
        _Pragma("unroll")                                                \
        for (int off = 1; off <= 8; off <<= 1)                           \
            mx = fmaxf(mx, __shfl_xor(mx, off));                        \
        const bool live_ = (j0 <= rr_);                                  \
        f4 p;                                                            \
        p.x = live_ ? __expf(sv.x - mx) : 0.f;                           \
        p.y = live_ ? __expf(sv.y - mx) : 0.f;                           \
        p.z = live_ ? __expf(sv.z - mx) : 0.f;                           \
        p.w = live_ ? __expf(sv.w - mx) : 0.f;                           \
        if (cq4 == 0) *(f4*)&pbuf[w8][R][jq * 4] = p;                    \
        float ls = (p.x + p.y) + (p.z + p.w);                            \
        _Pragma("unroll")                                                \
        for (int off = 1; off <= 8; off <<= 1)                           \
            ls += __shfl_xor(ls, off);                                   \
        MD = live_ ? mx : -1e30f;                                        \
        LD = ls;                                                         \
    }
    FINROW(0, s0, m0, l0)
    FINROW(1, s1, m1, l1)
    FINROW(2, s2, m2, l2)
    FINROW(3, s3, m3, l3)
#undef FINROW

    // ---- PV over the window; lane = h; V loads shared by 4 rows ----
    const float* vt = Vv + ((size_t)b * 512 + j0) * 64 + lane;
    float a0 = 0.f, a1 = 0.f, a2 = 0.f, a3 = 0.f;
#pragma unroll 4
    for (int q4 = 0; q4 < 16; ++q4) {
        const f4 p0 = *(const f4*)&pbuf[w8][0][q4 * 4];
        const f4 p1 = *(const f4*)&pbuf[w8][1][q4 * 4];
        const f4 p2 = *(const f4*)&pbuf[w8][2][q4 * 4];
        const f4 p3 = *(const f4*)&pbuf[w8][3][q4 * 4];
        const float v0 = vt[(q4 * 4 + 0) * 64];
        const float v1 = vt[(q4 * 4 + 1) * 64];
        const float v2 = vt[(q4 * 4 + 2) * 64];
        const float v3 = vt[(q4 * 4 + 3) * 64];
        a0 += p0.x * v0 + p0.y * v1 + p0.z * v2 + p0.w * v3;
        a1 += p1.x * v0 + p1.y * v1 + p1.z * v2 + p1.w * v3;
        a2 += p2.x * v0 + p2.y * v1 + p2.z * v2 + p2.w * v3;
        a3 += p3.x * v0 + p3.y * v1 + p3.z * v2 + p3.w * v3;
    }

    // ---- write partials: key = (global row)*8 + w ----
    const size_t k0 = ((size_t)(b * 512 + r0) * 8 + w);
    pacc[(k0 + 0 ) * 64 + lane] = a0;
    pacc[(k0 + 8 ) * 64 + lane] = a1;
    pacc[(k0 + 16) * 64 + lane] = a2;
    pacc[(k0 + 24) * 64 + lane] = a3;
    if (lane == 0) {
        pml[(k0 + 0 ) * 2] = m0;  pml[(k0 + 0 ) * 2 + 1] = l0;
        pml[(k0 + 8 ) * 2] = m1;  pml[(k0 + 8 ) * 2 + 1] = l1;
        pml[(k0 + 16) * 2] = m2;  pml[(k0 + 16) * 2 + 1] = l2;
        pml[(k0 + 24) * 2] = m3;  pml[(k0 + 24) * 2 + 1] = l3;
    }
}

// ---------------------------------------------------------------------------
// Kernel 3: merge. One wave per row; flash-combine its nw = i/64 + 1
// window partials. (round 11 verbatim — verified)
// ---------------------------------------------------------------------------
__global__ __launch_bounds__(256) void k_merge(
    const float* __restrict__ pml, const float* __restrict__ pacc,
    float* __restrict__ out)
{
    const int t = threadIdx.x;
    const int w8 = t >> 6, lane = t & 63;
    const int grow = blockIdx.x * 4 + w8;   // 0..2047
    const int i = grow & 511;
    const int nw = (i >> 6) + 1;
    const size_t base = (size_t)grow * 8;

    float ms = -1e30f;
    for (int w = 0; w < nw; ++w) ms = fmaxf(ms, pml[(base + w) * 2]);
    float num = 0.f, den = 0.f;
    for (int w = 0; w < nw; ++w) {
        const float e = __expf(pml[(base + w) * 2] - ms);
        den += pml[(base + w) * 2 + 1] * e;
        num += pacc[(base + w) * 64 + lane] * e;
    }
    out[(size_t)grow * 64 + lane] = num / den;
}

// ---------------------------------------------------------------------------
extern "C" void kernel_launch(void* const* d_in, const int* in_sizes, int n_in,
                              void* d_out, int out_size, void* d_ws, size_t ws_size,
                              hipStream_t stream)
{
    const float* x   = (const float*)d_in[0];
    const float* pos = (const float*)d_in[1];
    const float* W1  = (const float*)d_in[2];
    const float* b1  = (const float*)d_in[3];
    const float* W2  = (const float*)d_in[4];
    const float* b2  = (const float*)d_in[5];  (void)b2;  // cancels in softmax
    const float* Wv  = (const float*)d_in[6];
    float* out = (float*)d_out;
    float* ws = (float*)d_ws;

    float* Aq   = ws;                 // B*T*C   = 262144
    float* AkT  = ws + 262144;        // B*C*T   = 262144 (transposed)
    float* V    = ws + 524288;        // B*T*HS  = 131072
    float* pml  = ws + 655360;        // 2048*8*2  = 32768
    float* pacc = ws + 688128;        // 2048*8*64 = 1048576

    k_prep<<<dim3(256), dim3(640), 0, stream>>>(x, pos, W1, b1, Wv, Aq, AkT, V);
    k_fusedp<<<dim3(144, B_), dim3(256), 0, stream>>>(Aq, AkT, V, W2, pml, pacc);
    k_merge<<<dim3(512), dim3(256), 0, stream>>>(pml, pacc, out);
}

// Round 20
// 34.745 us; speedup vs baseline: 2.1651x; 1.1551x over previous
//
#include <hip/hip_runtime.h>
#include <math.h>

#define B_ 4
#define T_ 512
#define C_ 128
#define HS_ 64

typedef float f4 __attribute__((ext_vector_type(4)));
typedef float f2 __attribute__((ext_vector_type(2)));

// scale = C^-0.5
#define SCALE_ 0.08838834764831845f

// relu on f2 WITHOUT breaking SLP vectorization: componentwise fmaxf
// scalarizes the surrounding add/mul chain; __builtin_elementwise_max keeps
// the whole chain in f2 form so the backend can emit v_pk_{add,max,fma}_f32.
static __device__ __forceinline__ f2 relu2(f2 v) {
#if __has_builtin(__builtin_elementwise_max)
    return __builtin_elementwise_max(v, (f2){0.f, 0.f});
#else
    v.x = fmaxf(v.x, 0.f);
    v.y = fmaxf(v.y, 0.f);
    return v;
#endif
}

// ---------------------------------------------------------------------------
// Kernel 1: prep.  x1 = x + pos_emb;  Aq = x1@W1q + b1;  AkT = (x1@W1k)^T;
// V = x@Wv.  256 blocks x 640 threads, block = 8 rows.  (round 10 verbatim)
// ---------------------------------------------------------------------------
__global__ __launch_bounds__(640) void k_prep(
    const float* __restrict__ x, const float* __restrict__ pos,
    const float* __restrict__ W1, const float* __restrict__ b1,
    const float* __restrict__ Wv,
    float* __restrict__ Aq, float* __restrict__ AkT, float* __restrict__ V)
{
    __shared__ float x1s[8 * 132];
    __shared__ float xs[8 * 132];
    const int t = threadIdx.x;
    const int row0 = blockIdx.x * 8;  // over B*T = 2048

    if (t < 256) {
        int r = t >> 5, cq = t & 31;
        int gr = row0 + r;
        f4 xv = *(const f4*)(x + gr * 128 + cq * 4);
        f4 pv = *(const f4*)(pos + (gr & 511) * 128 + cq * 4);
        *(f4*)&xs[r * 132 + cq * 4] = xv;
        *(f4*)&x1s[r * 132 + cq * 4] = xv + pv;
    }
    __syncthreads();

    const int q = t >> 3;   // 0..79 col-quad
    const int r = t & 7;    // row in tile

    const float* wbase;
    int wstr, col0;
    const float* xb;
    f4 binit = {0.f, 0.f, 0.f, 0.f};
    if (q < 32) {
        col0 = q * 4;
        wbase = W1 + 128 * 128 + col0;  // W1q rows (c-major)
        wstr = 128;
        xb = x1s;
        binit = *(const f4*)(b1 + col0);
    } else if (q < 64) {
        col0 = (q - 32) * 4;
        wbase = W1 + col0;  // W1k rows
        wstr = 128;
        xb = x1s;
    } else {
        col0 = (q - 64) * 4;
        wbase = Wv + col0;
        wstr = 64;
        xb = xs;
    }

    f4 acc = binit;
    const float* xr = xb + r * 132;
#pragma unroll 8
    for (int c = 0; c < 128; ++c) {
        f4 w = *(const f4*)(wbase + c * wstr);
        acc += xr[c] * w;
    }

    const int gr = row0 + r;
    if (q < 32) {
        *(f4*)(Aq + (size_t)gr * 128 + col0) = acc;
    } else if (q < 64) {
        const int bb = gr >> 9, j = gr & 511;
        float* base = AkT + ((size_t)bb * 128 + col0) * 512 + j;
        base[0]    = acc.x;
        base[512]  = acc.y;
        base[1024] = acc.z;
        base[1536] = acc.w;
    } else {
        *(f4*)(V + (size_t)gr * 64 + col0) = acc;
    }
}

// ---------------------------------------------------------------------------
// Kernel 2: fused wei + causal softmax + PV, ROW QUAD, balanced chunks
// (round 15 structure — measured champion) with two issue-level fixes:
//   (1) relu2 via __builtin_elementwise_max -> packed v_pk_*_f32 S-chain.
//   (2) the 4 rows' max/sum shuffle reductions INTERLEAVED so the 8
//       formerly-serial 6-shfl chains pipeline their DS latency.
// Everything else (masks, chunking, PV, in-block merge) is R15-verbatim.
// ---------------------------------------------------------------------------
__global__ __launch_bounds__(256, 4) void k_fused(
    const float* __restrict__ Aq, const float* __restrict__ AkT,
    const float* __restrict__ Vv, const float* __restrict__ W2,
    float* __restrict__ out)
{
    __shared__ float pbuf[4][4][128];
    __shared__ float accs[4][4][64];
    __shared__ float mls[4][4][2];

    const int t = threadIdx.x;
    const int bx = blockIdx.x;         // 0..511
    const int b = bx & 3;
    const int g = 127 - (bx >> 2);     // descending: heavy quads first
    const int r0 = g * 4;
    const int w = t >> 6, lane = t & 63;

    const int nj = r0 + 4;                      // live j count for this quad
    const int cj = ((nj + 7) >> 3) << 1;        // per-wave chunk, even, <=128
    const int jstart = w * cj;
    const int jend = min(jstart + cj, nj);
    const int jA = jstart + lane * 2;

    float m0 = -1e30f, m1 = -1e30f, m2 = -1e30f, m3 = -1e30f;
    float l0 = 0.f, l1 = 0.f, l2 = 0.f, l3 = 0.f;
    float a0 = 0.f, a1 = 0.f, a2 = 0.f, a3 = 0.f;

    if (jstart < jend) {
        const float* aq0 = Aq + (size_t)(b * 512 + r0) * 128;
        const float* aq1 = aq0 + 128;
        const float* aq2 = aq1 + 128;
        const float* aq3 = aq2 + 128;
        const float* akt = AkT + (size_t)b * 65536 + jA;  // jA <= 510 always

        f2 s0a = {0,0}, s0b = {0,0}, s1a = {0,0}, s1b = {0,0};
        f2 s2a = {0,0}, s2b = {0,0}, s3a = {0,0}, s3b = {0,0};
#pragma unroll 4
        for (int c = 0; c < 128; c += 2) {
            const f2 k0 = *(const f2*)(akt + (size_t)c * 512);
            const f2 k1 = *(const f2*)(akt + (size_t)(c + 1) * 512);
            const float w0 = W2[c], w1 = W2[c + 1];
            s0a += relu2(k0 + aq0[c]) * w0;  s0b += relu2(k1 + aq0[c + 1]) * w1;
            s1a += relu2(k0 + aq1[c]) * w0;  s1b += relu2(k1 + aq1[c + 1]) * w1;
            s2a += relu2(k0 + aq2[c]) * w0;  s2b += relu2(k1 + aq2[c + 1]) * w1;
            s3a += relu2(k0 + aq3[c]) * w0;  s3b += relu2(k1 + aq3[c + 1]) * w1;
        }

        // ---- masked scores (R15 semantics) ----
        const int jl0 = min(jend - 1, r0 + 0);
        const int jl1 = min(jend - 1, r0 + 1);
        const int jl2 = min(jend - 1, r0 + 2);
        const int jl3 = min(jend - 1, r0 + 3);
        const f2 sv0 = (s0a + s0b) * SCALE_;
        const f2 sv1 = (s1a + s1b) * SCALE_;
        const f2 sv2 = (s2a + s2b) * SCALE_;
        const f2 sv3 = (s3a + s3b) * SCALE_;
        const float sx0 = (jA     <= jl0) ? sv0.x : -1e30f;
        const float sy0 = (jA + 1 <= jl0) ? sv0.y : -1e30f;
        const float sx1 = (jA     <= jl1) ? sv1.x : -1e30f;
        const float sy1 = (jA + 1 <= jl1) ? sv1.y : -1e30f;
        const float sx2 = (jA     <= jl2) ? sv2.x : -1e30f;
        const float sy2 = (jA + 1 <= jl2) ? sv2.y : -1e30f;
        const float sx3 = (jA     <= jl3) ? sv3.x : -1e30f;
        const float sy3 = (jA + 1 <= jl3) ? sv3.y : -1e30f;

        // ---- interleaved 4-row max reduce (independent shfl chains) ----
        float mx0 = fmaxf(sx0, sy0);
        float mx1 = fmaxf(sx1, sy1);
        float mx2 = fmaxf(sx2, sy2);
        float mx3 = fmaxf(sx3, sy3);
#pragma unroll
        for (int off = 1; off < 64; off <<= 1) {
            mx0 = fmaxf(mx0, __shfl_xor(mx0, off));
            mx1 = fmaxf(mx1, __shfl_xor(mx1, off));
            mx2 = fmaxf(mx2, __shfl_xor(mx2, off));
            mx3 = fmaxf(mx3, __shfl_xor(mx3, off));
        }

        const bool lv0 = (jstart <= r0 + 0);
        const bool lv1 = (jstart <= r0 + 1);
        const bool lv2 = (jstart <= r0 + 2);
        const bool lv3 = (jstart <= r0 + 3);
        const float px0 = lv0 ? __expf(sx0 - mx0) : 0.f;
        const float py0 = lv0 ? __expf(sy0 - mx0) : 0.f;
        const float px1 = lv1 ? __expf(sx1 - mx1) : 0.f;
        const float py1 = lv1 ? __expf(sy1 - mx1) : 0.f;
        const float px2 = lv2 ? __expf(sx2 - mx2) : 0.f;
        const float py2 = lv2 ? __expf(sy2 - mx2) : 0.f;
        const float px3 = lv3 ? __expf(sx3 - mx3) : 0.f;
        const float py3 = lv3 ? __expf(sy3 - mx3) : 0.f;
        *(f2*)&pbuf[w][0][lane * 2] = (f2){px0, py0};
        *(f2*)&pbuf[w][1][lane * 2] = (f2){px1, py1};
        *(f2*)&pbuf[w][2][lane * 2] = (f2){px2, py2};
        *(f2*)&pbuf[w][3][lane * 2] = (f2){px3, py3};

        // ---- interleaved 4-row sum reduce ----
        float ls0 = px0 + py0;
        float ls1 = px1 + py1;
        float ls2 = px2 + py2;
        float ls3 = px3 + py3;
#pragma unroll
        for (int off = 1; off < 64; off <<= 1) {
            ls0 += __shfl_xor(ls0, off);
            ls1 += __shfl_xor(ls1, off);
            ls2 += __shfl_xor(ls2, off);
            ls3 += __shfl_xor(ls3, off);
        }
        m0 = lv0 ? mx0 : -1e30f;  l0 = ls0;
        m1 = lv1 ? mx1 : -1e30f;  l1 = ls1;
        m2 = lv2 ? mx2 : -1e30f;  l2 = ls2;
        m3 = lv3 ? mx3 : -1e30f;  l3 = ls3;

        // ---- PV over the chunk; lane = h; V loads shared by 4 rows ----
        const float* vt = Vv + ((size_t)b * 512 + jstart) * 64 + lane;
        const int q4max = (jend - jstart + 3) >> 2;
        for (int q4 = 0; q4 < q4max; ++q4) {
            const f4 p0 = *(const f4*)&pbuf[w][0][q4 * 4];
            const f4 p1 = *(const f4*)&pbuf[w][1][q4 * 4];
            const f4 p2 = *(const f4*)&pbuf[w][2][q4 * 4];
            const f4 p3 = *(const f4*)&pbuf[w][3][q4 * 4];
            const float v0 = vt[(q4 * 4 + 0) * 64];
            const float v1 = vt[(q4 * 4 + 1) * 64];
            const float v2 = vt[(q4 * 4 + 2) * 64];
            const float v3 = vt[(q4 * 4 + 3) * 64];
            a0 += p0.x * v0 + p0.y * v1 + p0.z * v2 + p0.w * v3;
            a1 += p1.x * v0 + p1.y * v1 + p1.z * v2 + p1.w * v3;
            a2 += p2.x * v0 + p2.y * v1 + p2.z * v2 + p2.w * v3;
            a3 += p3.x * v0 + p3.y * v1 + p3.z * v2 + p3.w * v3;
        }
    }

    // ---- partials to LDS; in-block flash merge ----
    accs[w][0][lane] = a0;
    accs[w][1][lane] = a1;
    accs[w][2][lane] = a2;
    accs[w][3][lane] = a3;
    if (lane == 0) {
        mls[w][0][0] = m0; mls[w][0][1] = l0;
        mls[w][1][0] = m1; mls[w][1][1] = l1;
        mls[w][2][0] = m2; mls[w][2][1] = l2;
        mls[w][3][0] = m3; mls[w][3][1] = l3;
    }
    __syncthreads();

    // wave w merges row r0 + w over all 4 wave partials
    const int rr = r0 + w;
    float ms = -1e30f;
#pragma unroll
    for (int ww = 0; ww < 4; ++ww) ms = fmaxf(ms, mls[ww][w][0]);
    float num = 0.f, den = 0.f;
#pragma unroll
    for (int ww = 0; ww < 4; ++ww) {
        const float e = __expf(mls[ww][w][0] - ms);
        den += mls[ww][w][1] * e;
        num += accs[ww][w][lane] * e;
    }
    out[(size_t)(b * 512 + rr) * 64 + lane] = num / den;
}

// ---------------------------------------------------------------------------
extern "C" void kernel_launch(void* const* d_in, const int* in_sizes, int n_in,
                              void* d_out, int out_size, void* d_ws, size_t ws_size,
                              hipStream_t stream)
{
    const float* x   = (const float*)d_in[0];
    const float* pos = (const float*)d_in[1];
    const float* W1  = (const float*)d_in[2];
    const float* b1  = (const float*)d_in[3];
    const float* W2  = (const float*)d_in[4];
    const float* b2  = (const float*)d_in[5];  (void)b2;  // cancels in softmax
    const float* Wv  = (const float*)d_in[6];
    float* out = (float*)d_out;
    float* ws = (float*)d_ws;

    float* Aq  = ws;                 // B*T*C = 262144
    float* AkT = ws + 262144;        // B*C*T = 262144 (transposed)
    float* V   = ws + 524288;        // B*T*HS = 131072

    k_prep<<<dim3(256), dim3(640), 0, stream>>>(x, pos, W1, b1, Wv, Aq, AkT, V);
    k_fused<<<dim3(512), dim3(256), 0, stream>>>(Aq, AkT, V, W2, out);
}